// Round 1
// baseline (626.617 us; speedup 1.0000x reference)
//
#include <hip/hip_runtime.h>
#include <math.h>

#define N_ROWS 32768
#define C_DIM 256
#define K_CODES 1024
#define DECAY_F 0.99f
#define ONE_MINUS_DECAY 0.01f
#define EPS_F 1e-5f

// Output offsets (floats)
#define OFF_QST 0
#define OFF_EMB 8388608
#define OFF_CS  8650752
#define OFF_DW  8651776
#define OFF_LOSS 8913920
#define OFF_PERP 8913921

// Workspace layout (float offsets)
#define WS_ESQ   0         // 1024
#define WS_ET    1024      // 262144  ET[k][c]
#define WS_DWT   263168    // 262144  dwT[k][c] accumulator
#define WS_CNT   525312    // 1024
#define WS_LOSSP 526336    // 8192
#define WS_INVSM 534528    // 1024
#define WS_IDX   535552    // 32768 ints

// ---------------- prep: esq[k] = sum_d E[d,k]^2 ----------------
__global__ __launch_bounds__(256) void esq_kernel(const float* __restrict__ E,
                                                  float* __restrict__ esq) {
    int k = blockIdx.x * 256 + threadIdx.x;
    float s = 0.f;
    #pragma unroll 8
    for (int d = 0; d < C_DIM; ++d) {
        float e = E[d * K_CODES + k];
        s += e * e;
    }
    esq[k] = s;
}

// ---------------- prep: ET[k][c] = E[c][k] ----------------
__global__ __launch_bounds__(256) void transpose_kernel(const float* __restrict__ E,
                                                        float* __restrict__ ET) {
    __shared__ float t[32][33];
    int bk = blockIdx.x & 31;       // 32 tiles along K
    int bc = blockIdx.x >> 5;       // 8 tiles along C
    int tx = threadIdx.x & 31;
    int ty = threadIdx.x >> 5;      // 0..7
    int k0 = bk * 32, c0 = bc * 32;
    #pragma unroll
    for (int i = 0; i < 4; ++i)
        t[ty + i * 8][tx] = E[(c0 + ty + i * 8) * K_CODES + k0 + tx];
    __syncthreads();
    #pragma unroll
    for (int i = 0; i < 4; ++i)
        ET[(k0 + ty + i * 8) * C_DIM + c0 + tx] = t[tx][ty + i * 8];
}

// ---------------- distance + argmin ----------------
// 256 threads, 32 rows/block. Thread (tr=tid>>4, tc=tid&15) owns rows {tr, tr+16}
// and codes {k0 + q*64 + tc*4 + j2} per 256-code chunk.
__global__ __launch_bounds__(256) void dist_kernel(const float* __restrict__ flat,
                                                   const float* __restrict__ E,
                                                   const float* __restrict__ esq,
                                                   int* __restrict__ idxbuf) {
    __shared__ float xs[32][257];
    int tid = threadIdx.x;
    int row0 = blockIdx.x * 32;
    for (int t = tid; t < 32 * 256; t += 256) {
        int r = t >> 8, d = t & 255;
        xs[r][d] = flat[(row0 + r) * C_DIM + d];
    }
    __syncthreads();
    int tr = tid >> 4;
    int tc = tid & 15;
    const float* xrow0 = xs[tr];
    const float* xrow1 = xs[tr + 16];
    float best0 = -INFINITY, best1 = -INFINITY;
    int bi0 = 0, bi1 = 0;

    for (int k0 = 0; k0 < K_CODES; k0 += 256) {
        float acc0[16], acc1[16];
        #pragma unroll
        for (int j = 0; j < 16; ++j) { acc0[j] = 0.f; acc1[j] = 0.f; }
        const float* Ebase = E + k0 + tc * 4;
        #pragma unroll 2
        for (int d = 0; d < C_DIM; ++d) {
            float x0 = xrow0[d];
            float x1 = xrow1[d];
            float e[16];
            *(float4*)(e + 0)  = *(const float4*)(Ebase + d * K_CODES + 0);
            *(float4*)(e + 4)  = *(const float4*)(Ebase + d * K_CODES + 64);
            *(float4*)(e + 8)  = *(const float4*)(Ebase + d * K_CODES + 128);
            *(float4*)(e + 12) = *(const float4*)(Ebase + d * K_CODES + 192);
            #pragma unroll
            for (int j = 0; j < 16; ++j) {
                acc0[j] += x0 * e[j];
                acc1[j] += x1 * e[j];
            }
        }
        #pragma unroll
        for (int q = 0; q < 4; ++q) {
            #pragma unroll
            for (int j2 = 0; j2 < 4; ++j2) {
                int k = k0 + q * 64 + tc * 4 + j2;
                float sq = esq[k];
                float s0 = 2.f * acc0[q * 4 + j2] - sq;
                float s1 = 2.f * acc1[q * 4 + j2] - sq;
                if (s0 > best0) { best0 = s0; bi0 = k; }
                if (s1 > best1) { best1 = s1; bi1 = k; }
            }
        }
    }
    // reduce across tc (16 lanes; argmax with min-index tie-break)
    #pragma unroll
    for (int m = 1; m < 16; m <<= 1) {
        float o = __shfl_xor(best0, m, 64);
        int oi   = __shfl_xor(bi0, m, 64);
        if (o > best0 || (o == best0 && oi < bi0)) { best0 = o; bi0 = oi; }
        o  = __shfl_xor(best1, m, 64);
        oi = __shfl_xor(bi1, m, 64);
        if (o > best1 || (o == best1 && oi < bi1)) { best1 = o; bi1 = oi; }
    }
    if (tc == 0) {
        idxbuf[row0 + tr] = bi0;
        idxbuf[row0 + 16 + tr] = bi1;
    }
}

// ---------------- gather: quant_st, dwT scatter, counts, loss partials ----------------
__global__ __launch_bounds__(256) void gather_kernel(const float* __restrict__ flat,
                                                     const float* __restrict__ ET,
                                                     const int* __restrict__ idxbuf,
                                                     float* __restrict__ out_qst,
                                                     float* __restrict__ dwT,
                                                     float* __restrict__ counts,
                                                     float* __restrict__ lossp) {
    int tid = threadIdx.x;
    int lane = tid & 63;
    int row = blockIdx.x * 4 + (tid >> 6);
    int k = idxbuf[row];
    float4 x = *(const float4*)&flat[row * C_DIM + lane * 4];
    float4 q = *(const float4*)&ET[k * C_DIM + lane * 4];
    float4 d4;
    d4.x = q.x - x.x; d4.y = q.y - x.y; d4.z = q.z - x.z; d4.w = q.w - x.w;
    float4 o;
    o.x = x.x + d4.x; o.y = x.y + d4.y; o.z = x.z + d4.z; o.w = x.w + d4.w;
    *(float4*)&out_qst[row * C_DIM + lane * 4] = o;

    float* dwp = &dwT[k * C_DIM + lane * 4];
    unsafeAtomicAdd(dwp + 0, x.x);
    unsafeAtomicAdd(dwp + 1, x.y);
    unsafeAtomicAdd(dwp + 2, x.z);
    unsafeAtomicAdd(dwp + 3, x.w);
    if (lane == 0) unsafeAtomicAdd(&counts[k], 1.0f);

    float ls = d4.x * d4.x + d4.y * d4.y + d4.z * d4.z + d4.w * d4.w;
    #pragma unroll
    for (int m = 1; m < 64; m <<= 1) ls += __shfl_xor(ls, m, 64);
    __shared__ float sm4[4];
    if (lane == 0) sm4[tid >> 6] = ls;
    __syncthreads();
    if (tid == 0) lossp[blockIdx.x] = sm4[0] + sm4[1] + sm4[2] + sm4[3];
}

// ---------------- finalize 1: cs EMA, n, smoothing, entropy, loss ----------------
__global__ __launch_bounds__(1024) void finalize1_kernel(const float* __restrict__ ema_cs,
                                                         const float* __restrict__ counts,
                                                         const float* __restrict__ lossp,
                                                         float* __restrict__ out,
                                                         float* __restrict__ inv_sm) {
    int k = threadIdx.x;
    __shared__ double red[1024];
    float cs = counts[k];
    float necs = ema_cs[k] * DECAY_F + cs * ONE_MINUS_DECAY;
    out[OFF_CS + k] = necs;

    red[k] = (double)necs;
    __syncthreads();
    for (int s = 512; s > 0; s >>= 1) {
        if (k < s) red[k] += red[k + s];
        __syncthreads();
    }
    float nf = (float)red[0];
    __syncthreads();

    float sm = (necs + EPS_F) / (nf + (float)K_CODES * EPS_F) * nf;
    inv_sm[k] = 1.0f / sm;

    float avg = cs * (1.0f / (float)N_ROWS);
    red[k] = (double)(avg * logf(avg + 1e-10f));
    __syncthreads();
    for (int s = 512; s > 0; s >>= 1) {
        if (k < s) red[k] += red[k + s];
        __syncthreads();
    }
    double ent = red[0];
    __syncthreads();

    double lp = 0.0;
    for (int i = k; i < 8192; i += 1024) lp += (double)lossp[i];
    red[k] = lp;
    __syncthreads();
    for (int s = 512; s > 0; s >>= 1) {
        if (k < s) red[k] += red[k + s];
        __syncthreads();
    }
    if (k == 0) {
        double eloss = red[0] / (double)(N_ROWS * C_DIM);
        out[OFF_LOSS] = (float)(0.25 * eloss);
        out[OFF_PERP] = expf((float)(-ent));
    }
}

// ---------------- finalize 2: new_ema_dw, new_embeddings ----------------
__global__ __launch_bounds__(256) void finalize2_kernel(const float* __restrict__ ema_dw,
                                                        const float* __restrict__ dwT,
                                                        const float* __restrict__ inv_sm,
                                                        float* __restrict__ out) {
    int i = blockIdx.x * 256 + threadIdx.x;   // over 262144 = [c][k]
    int c = i >> 10;
    int k = i & 1023;
    float ndw = ema_dw[i] * DECAY_F + dwT[k * C_DIM + c] * ONE_MINUS_DECAY;
    out[OFF_DW + i] = ndw;
    out[OFF_EMB + i] = ndw * inv_sm[k];
}

extern "C" void kernel_launch(void* const* d_in, const int* in_sizes, int n_in,
                              void* d_out, int out_size, void* d_ws, size_t ws_size,
                              hipStream_t stream) {
    const float* inputs = (const float*)d_in[0];
    const float* E      = (const float*)d_in[1];
    const float* ema_cs = (const float*)d_in[2];
    const float* ema_dw = (const float*)d_in[3];
    float* out = (float*)d_out;
    float* ws  = (float*)d_ws;

    float* esq    = ws + WS_ESQ;
    float* ET     = ws + WS_ET;
    float* dwT    = ws + WS_DWT;
    float* counts = ws + WS_CNT;
    float* lossp  = ws + WS_LOSSP;
    float* inv_sm = ws + WS_INVSM;
    int*   idxbuf = (int*)(ws + WS_IDX);

    // zero dwT + counts (atomic accumulators)
    hipMemsetAsync(ws + WS_DWT, 0, (size_t)(K_CODES * C_DIM + K_CODES) * sizeof(float), stream);

    esq_kernel<<<K_CODES / 256, 256, 0, stream>>>(E, esq);
    transpose_kernel<<<256, 256, 0, stream>>>(E, ET);
    dist_kernel<<<N_ROWS / 32, 256, 0, stream>>>(inputs, E, esq, idxbuf);
    gather_kernel<<<N_ROWS / 4, 256, 0, stream>>>(inputs, ET, idxbuf, out + OFF_QST,
                                                  dwT, counts, lossp);
    finalize1_kernel<<<1, 1024, 0, stream>>>(ema_cs, counts, lossp, out, inv_sm);
    finalize2_kernel<<<(C_DIM * K_CODES) / 256, 256, 0, stream>>>(ema_dw, dwT, inv_sm, out);
}

// Round 2
// 236.766 us; speedup vs baseline: 2.6466x; 2.6466x over previous
//
#include <hip/hip_runtime.h>
#include <hip/hip_bf16.h>
#include <math.h>

#define N_ROWS 32768
#define C_DIM 256
#define K_CODES 1024
#define DECAY_F 0.99f
#define ONE_MINUS_DECAY 0.01f
#define EPS_F 1e-5f

// Output offsets (floats)
#define OFF_QST 0
#define OFF_EMB 8388608
#define OFF_CS  8650752
#define OFF_DW  8651776
#define OFF_LOSS 8913920
#define OFF_PERP 8913921

// Workspace layout (float offsets). Bp (bf16-packed E, 1MB) overlays the ET
// region: b_pack+mfma_dist use it first, then transpose_kernel overwrites it
// with ET for gather (stream-ordered).
#define WS_ESQ   0         // 1024
#define WS_ET    1024      // 262144 floats = 1MB: Bp (shorts) then ET
#define WS_DWT   263168    // 262144
#define WS_CNT   525312    // 1024
#define WS_LOSSP 526336    // 8192
#define WS_INVSM 534528    // 1024
#define WS_IDX   535552    // 32768 ints

typedef __attribute__((ext_vector_type(8))) short bf16x8;
typedef __attribute__((ext_vector_type(4))) float f32x4;
typedef union { short s[8]; unsigned u[4]; bf16x8 v; } fragu;

__device__ inline unsigned bf16rne(float f) {
    unsigned u = __float_as_uint(f);
    return (u + 0x7fffu + ((u >> 16) & 1u)) >> 16;
}

__device__ inline unsigned pack_bf16_pair(float a, float b) {
    float2 f2; f2.x = a; f2.y = b;
    __hip_bfloat162 h = __float22bfloat162_rn(f2);   // -> v_cvt_pk_bf16_f32
    union { __hip_bfloat162 b2; unsigned u; } cv;
    cv.b2 = h;
    return cv.u;
}

// ---------------- prep: esq[k] = sum_d E[d,k]^2 ----------------
__global__ __launch_bounds__(256) void esq_kernel(const float* __restrict__ E,
                                                  float* __restrict__ esq) {
    int k = blockIdx.x * 256 + threadIdx.x;
    float s = 0.f;
    #pragma unroll 8
    for (int d = 0; d < C_DIM; ++d) {
        float e = E[d * K_CODES + k];
        s += e * e;
    }
    esq[k] = s;
}

// ---------------- prep: pack E into MFMA B-fragment layout ----------------
// Bp group g = ct*16 + ks  (ct: col-tile 0..63, ks: packed k-step 0..15;
// ks<8 -> e_hi rows k=(ks)*32.., ks>=8 -> e_lo rows k=(ks-8)*32..).
// Within group: lane l holds 8 bf16: col = ct*16+(l&15), k += (l>>4)*8 + b.
__global__ __launch_bounds__(256) void b_pack_kernel(const float* __restrict__ E,
                                                     short* __restrict__ Bp) {
    int tid = threadIdx.x;
    int g = blockIdx.x * 4 + (tid >> 6);
    int l = tid & 63;
    int ct = g >> 4, ks = g & 15;
    int j = ct * 16 + (l & 15);
    int kbase = (ks & 7) * 32 + (l >> 4) * 8;
    fragu out;
    #pragma unroll
    for (int b = 0; b < 8; ++b) {
        float e = E[(kbase + b) * K_CODES + j];
        unsigned hi = bf16rne(e);
        if (ks < 8) out.s[b] = (short)hi;
        else        out.s[b] = (short)bf16rne(e - __uint_as_float(hi << 16));
    }
    *(bf16x8*)(Bp + ((size_t)g * 64 + l) * 8) = out.v;
}

// ---------------- prep: ET[k][c] = E[c][k] (for gather) ----------------
__global__ __launch_bounds__(256) void transpose_kernel(const float* __restrict__ E,
                                                        float* __restrict__ ET) {
    __shared__ float t[32][33];
    int bk = blockIdx.x & 31;
    int bc = blockIdx.x >> 5;
    int tx = threadIdx.x & 31;
    int ty = threadIdx.x >> 5;
    int k0 = bk * 32, c0 = bc * 32;
    #pragma unroll
    for (int i = 0; i < 4; ++i)
        t[ty + i * 8][tx] = E[(c0 + ty + i * 8) * K_CODES + k0 + tx];
    __syncthreads();
    #pragma unroll
    for (int i = 0; i < 4; ++i)
        ET[(k0 + ty + i * 8) * C_DIM + c0 + tx] = t[tx][ty + i * 8];
}

// ---------------- MFMA distance + fused argmax ----------------
// 256 thr = 4 waves; wave owns 32 rows (2 row-tiles of 16). Chunks of 256
// codes (16 col-tiles); acc[2][16] f32x4. Split-bf16: s = xh*eh + xh*el + xl*eh.
__global__ __launch_bounds__(256, 1) void mfma_dist_kernel(
    const float* __restrict__ X,
    const short* __restrict__ Bp,
    const float* __restrict__ esq,
    int* __restrict__ idxbuf)
{
    int tid = threadIdx.x;
    int w = tid >> 6, l = tid & 63;
    int row0 = blockIdx.x * 128 + w * 32;
    int arow = l & 15;
    int aseg = l >> 4;
    const float* X0 = X + (size_t)(row0 + arow) * C_DIM + aseg * 8;
    const float* X1 = X0 + 16 * C_DIM;

    float best[8];
    int bidx[8];
    #pragma unroll
    for (int i = 0; i < 8; ++i) { best[i] = -INFINITY; bidx[i] = 0; }

    for (int ch = 0; ch < 4; ++ch) {
        f32x4 acc[2][16];
        #pragma unroll
        for (int rt = 0; rt < 2; ++rt)
            #pragma unroll
            for (int ct = 0; ct < 16; ++ct)
                acc[rt][ct] = (f32x4)(0.f);

        #pragma unroll 2
        for (int ks = 0; ks < 8; ++ks) {
            // ---- A fragments: load fp32, split to bf16 hi/lo in-register ----
            float xf0[8], xf1[8];
            *(float4*)(xf0)     = *(const float4*)(X0 + ks * 32);
            *(float4*)(xf0 + 4) = *(const float4*)(X0 + ks * 32 + 4);
            *(float4*)(xf1)     = *(const float4*)(X1 + ks * 32);
            *(float4*)(xf1 + 4) = *(const float4*)(X1 + ks * 32 + 4);
            fragu ah0, al0, ah1, al1;
            #pragma unroll
            for (int p = 0; p < 4; ++p) {
                float a = xf0[2 * p], b = xf0[2 * p + 1];
                unsigned h = pack_bf16_pair(a, b);
                ah0.u[p] = h;
                al0.u[p] = pack_bf16_pair(a - __uint_as_float(h << 16),
                                          b - __uint_as_float(h & 0xffff0000u));
                float c = xf1[2 * p], d = xf1[2 * p + 1];
                unsigned h2 = pack_bf16_pair(c, d);
                ah1.u[p] = h2;
                al1.u[p] = pack_bf16_pair(c - __uint_as_float(h2 << 16),
                                          d - __uint_as_float(h2 & 0xffff0000u));
            }
            // ---- B fragments + MFMA ----
            const short* bbase = Bp + ((size_t)ch * 256 + ks) * 512 + l * 8;
            #pragma unroll
            for (int ct = 0; ct < 16; ++ct) {
                const short* bp = bbase + ct * 8192;
                bf16x8 bh = *(const bf16x8*)bp;
                bf16x8 bl = *(const bf16x8*)(bp + 4096);
                acc[0][ct] = __builtin_amdgcn_mfma_f32_16x16x32_bf16(ah0.v, bh, acc[0][ct], 0, 0, 0);
                acc[1][ct] = __builtin_amdgcn_mfma_f32_16x16x32_bf16(ah1.v, bh, acc[1][ct], 0, 0, 0);
                acc[0][ct] = __builtin_amdgcn_mfma_f32_16x16x32_bf16(al0.v, bh, acc[0][ct], 0, 0, 0);
                acc[1][ct] = __builtin_amdgcn_mfma_f32_16x16x32_bf16(al1.v, bh, acc[1][ct], 0, 0, 0);
                acc[0][ct] = __builtin_amdgcn_mfma_f32_16x16x32_bf16(ah0.v, bl, acc[0][ct], 0, 0, 0);
                acc[1][ct] = __builtin_amdgcn_mfma_f32_16x16x32_bf16(ah1.v, bl, acc[1][ct], 0, 0, 0);
            }
        }
        // ---- fused argmax epilogue (strict > keeps lowest col on ties) ----
        #pragma unroll
        for (int rt = 0; rt < 2; ++rt) {
            #pragma unroll
            for (int ct = 0; ct < 16; ++ct) {
                int col = ch * 256 + ct * 16 + (l & 15);
                float sq = esq[col];
                #pragma unroll
                for (int v = 0; v < 4; ++v) {
                    float s = 2.f * acc[rt][ct][v] - sq;
                    int bi = rt * 4 + v;
                    if (s > best[bi]) { best[bi] = s; bidx[bi] = col; }
                }
            }
        }
    }
    // cross-lane argmax over the 16 lanes sharing each row (min-index ties)
    #pragma unroll
    for (int bi = 0; bi < 8; ++bi) {
        float bv = best[bi]; int ix = bidx[bi];
        #pragma unroll
        for (int m = 1; m < 16; m <<= 1) {
            float ov = __shfl_xor(bv, m, 64);
            int oi = __shfl_xor(ix, m, 64);
            if (ov > bv || (ov == bv && oi < ix)) { bv = ov; ix = oi; }
        }
        if ((l & 15) == 0) {
            int rt = bi >> 2, v = bi & 3;
            idxbuf[row0 + rt * 16 + aseg * 4 + v] = ix;
        }
    }
}

// ---------------- gather: quant_st, dwT scatter, counts, loss partials ----------------
__global__ __launch_bounds__(256) void gather_kernel(const float* __restrict__ flat,
                                                     const float* __restrict__ ET,
                                                     const int* __restrict__ idxbuf,
                                                     float* __restrict__ out_qst,
                                                     float* __restrict__ dwT,
                                                     float* __restrict__ counts,
                                                     float* __restrict__ lossp) {
    int tid = threadIdx.x;
    int lane = tid & 63;
    int row = blockIdx.x * 4 + (tid >> 6);
    int k = idxbuf[row];
    float4 x = *(const float4*)&flat[row * C_DIM + lane * 4];
    float4 q = *(const float4*)&ET[k * C_DIM + lane * 4];
    float4 d4;
    d4.x = q.x - x.x; d4.y = q.y - x.y; d4.z = q.z - x.z; d4.w = q.w - x.w;
    float4 o;
    o.x = x.x + d4.x; o.y = x.y + d4.y; o.z = x.z + d4.z; o.w = x.w + d4.w;
    *(float4*)&out_qst[row * C_DIM + lane * 4] = o;

    float* dwp = &dwT[k * C_DIM + lane * 4];
    unsafeAtomicAdd(dwp + 0, x.x);
    unsafeAtomicAdd(dwp + 1, x.y);
    unsafeAtomicAdd(dwp + 2, x.z);
    unsafeAtomicAdd(dwp + 3, x.w);
    if (lane == 0) unsafeAtomicAdd(&counts[k], 1.0f);

    float ls = d4.x * d4.x + d4.y * d4.y + d4.z * d4.z + d4.w * d4.w;
    #pragma unroll
    for (int m = 1; m < 64; m <<= 1) ls += __shfl_xor(ls, m, 64);
    __shared__ float sm4[4];
    if (lane == 0) sm4[tid >> 6] = ls;
    __syncthreads();
    if (tid == 0) lossp[blockIdx.x] = sm4[0] + sm4[1] + sm4[2] + sm4[3];
}

// ---------------- finalize 1: cs EMA, n, smoothing, entropy, loss ----------------
__global__ __launch_bounds__(1024) void finalize1_kernel(const float* __restrict__ ema_cs,
                                                         const float* __restrict__ counts,
                                                         const float* __restrict__ lossp,
                                                         float* __restrict__ out,
                                                         float* __restrict__ inv_sm) {
    int k = threadIdx.x;
    __shared__ double red[1024];
    float cs = counts[k];
    float necs = ema_cs[k] * DECAY_F + cs * ONE_MINUS_DECAY;
    out[OFF_CS + k] = necs;

    red[k] = (double)necs;
    __syncthreads();
    for (int s = 512; s > 0; s >>= 1) {
        if (k < s) red[k] += red[k + s];
        __syncthreads();
    }
    float nf = (float)red[0];
    __syncthreads();

    float sm = (necs + EPS_F) / (nf + (float)K_CODES * EPS_F) * nf;
    inv_sm[k] = 1.0f / sm;

    float avg = cs * (1.0f / (float)N_ROWS);
    red[k] = (double)(avg * logf(avg + 1e-10f));
    __syncthreads();
    for (int s = 512; s > 0; s >>= 1) {
        if (k < s) red[k] += red[k + s];
        __syncthreads();
    }
    double ent = red[0];
    __syncthreads();

    double lp = 0.0;
    for (int i = k; i < 8192; i += 1024) lp += (double)lossp[i];
    red[k] = lp;
    __syncthreads();
    for (int s = 512; s > 0; s >>= 1) {
        if (k < s) red[k] += red[k + s];
        __syncthreads();
    }
    if (k == 0) {
        double eloss = red[0] / (double)(N_ROWS * C_DIM);
        out[OFF_LOSS] = (float)(0.25 * eloss);
        out[OFF_PERP] = expf((float)(-ent));
    }
}

// ---------------- finalize 2: new_ema_dw, new_embeddings ----------------
__global__ __launch_bounds__(256) void finalize2_kernel(const float* __restrict__ ema_dw,
                                                        const float* __restrict__ dwT,
                                                        const float* __restrict__ inv_sm,
                                                        float* __restrict__ out) {
    int i = blockIdx.x * 256 + threadIdx.x;
    int c = i >> 10;
    int k = i & 1023;
    float ndw = ema_dw[i] * DECAY_F + dwT[k * C_DIM + c] * ONE_MINUS_DECAY;
    out[OFF_DW + i] = ndw;
    out[OFF_EMB + i] = ndw * inv_sm[k];
}

extern "C" void kernel_launch(void* const* d_in, const int* in_sizes, int n_in,
                              void* d_out, int out_size, void* d_ws, size_t ws_size,
                              hipStream_t stream) {
    const float* inputs = (const float*)d_in[0];
    const float* E      = (const float*)d_in[1];
    const float* ema_cs = (const float*)d_in[2];
    const float* ema_dw = (const float*)d_in[3];
    float* out = (float*)d_out;
    float* ws  = (float*)d_ws;

    float* esq    = ws + WS_ESQ;
    float* ET     = ws + WS_ET;       // also Bp (shorts) before transpose runs
    short* Bp     = (short*)(ws + WS_ET);
    float* dwT    = ws + WS_DWT;
    float* counts = ws + WS_CNT;
    float* lossp  = ws + WS_LOSSP;
    float* inv_sm = ws + WS_INVSM;
    int*   idxbuf = (int*)(ws + WS_IDX);

    hipMemsetAsync(ws + WS_DWT, 0, (size_t)(K_CODES * C_DIM + K_CODES) * sizeof(float), stream);

    esq_kernel<<<K_CODES / 256, 256, 0, stream>>>(E, esq);
    b_pack_kernel<<<256, 256, 0, stream>>>(E, Bp);
    mfma_dist_kernel<<<N_ROWS / 128, 256, 0, stream>>>(inputs, Bp, esq, idxbuf);
    transpose_kernel<<<256, 256, 0, stream>>>(E, ET);   // overwrites Bp region
    gather_kernel<<<N_ROWS / 4, 256, 0, stream>>>(inputs, ET, idxbuf, out + OFF_QST,
                                                  dwT, counts, lossp);
    finalize1_kernel<<<1, 1024, 0, stream>>>(ema_cs, counts, lossp, out, inv_sm);
    finalize2_kernel<<<(C_DIM * K_CODES) / 256, 256, 0, stream>>>(ema_dw, dwT, inv_sm, out);
}